// Round 11
// baseline (164.032 us; speedup 1.0000x reference)
//
#include <hip/hip_runtime.h>

typedef unsigned short ushort_t;
typedef unsigned int uint_t;
typedef _Float16 f16;
typedef _Float16 f16x8 __attribute__((ext_vector_type(8)));
typedef float f32x4 __attribute__((ext_vector_type(4)));

constexpr int N    = 50000;
constexpr int E    = 800000;
constexpr int G    = 512;
constexpr int SCAN_ITEMS = 1024;
constexpr int NB_SCAN = (N + SCAN_ITEMS - 1) / SCAN_ITEMS;   // 49
constexpr int NBX = (N + 3) / 4;          // 12500 xd/finalize blocks
constexpr int NBS = (E + 255) / 256;      // 3125 scatter blocks

// zero edeg + cur (contiguous: 2 x 200,704 B = 25088 int4)
__global__ void k_zero(int4* __restrict__ p) {
    int i = blockIdx.x * blockDim.x + threadIdx.x;
    if (i < 25088) p[i] = int4{0, 0, 0, 0};
}

// degree count only (no rank)
__global__ void k_deg(const int* __restrict__ dst, int* __restrict__ edeg) {
    int e = blockIdx.x * blockDim.x + threadIdx.x;
    if (e < E) atomicAdd(&edeg[dst[e]], 1);
}

// block-level exclusive scan of edeg (1024 items / block); extra blocks repack W->f16 frags
__global__ __launch_bounds__(256) void k_scan1w(const int* __restrict__ edeg,
                                                int* __restrict__ row_ptr,
                                                int* __restrict__ bsum,
                                                const float* __restrict__ W1,
                                                const float* __restrict__ W2,
                                                f16* __restrict__ W1f,
                                                f16* __restrict__ W2f) {
    __shared__ int s[256];
    int t = threadIdx.x;
    if (blockIdx.x >= NB_SCAN) {
        int idx = (blockIdx.x - NB_SCAN) * 256 + t;
        if (idx < 8192) {
            int j = idx & 7, lane = (idx >> 3) & 63, c = (idx >> 9) & 7, kk = idx >> 12;
            int k = 32 * kk + 8 * (lane >> 4) + j, col = 16 * c + (lane & 15);
            W1f[idx] = (f16)W1[k * 128 + col];
        } else {
            int t2 = idx - 8192;
            int j = t2 & 7, lane = (t2 >> 3) & 63, c = (t2 >> 9) & 3, kk = (t2 >> 11) & 3;
            int k = 32 * kk + 8 * (lane >> 4) + j, col = 16 * c + (lane & 15);
            W2f[t2] = (f16)W2[k * 64 + col];
        }
        return;
    }
    int base = blockIdx.x * SCAN_ITEMS + t * 4;
    int v0 = (base + 0 < N) ? edeg[base + 0] : 0;
    int v1 = (base + 1 < N) ? edeg[base + 1] : 0;
    int v2 = (base + 2 < N) ? edeg[base + 2] : 0;
    int v3 = (base + 3 < N) ? edeg[base + 3] : 0;
    int tsum = v0 + v1 + v2 + v3;
    s[t] = tsum;
    __syncthreads();
    for (int off = 1; off < 256; off <<= 1) {
        int add = (t >= off) ? s[t - off] : 0;
        __syncthreads();
        s[t] += add;
        __syncthreads();
    }
    int texcl = s[t] - tsum;
    if (t == 255) bsum[blockIdx.x] = s[255];
    if (base + 0 < N) row_ptr[base + 0] = texcl;
    if (base + 1 < N) row_ptr[base + 1] = texcl + v0;
    if (base + 2 < N) row_ptr[base + 2] = texcl + v0 + v1;
    if (base + 3 < N) row_ptr[base + 3] = texcl + v0 + v1 + v2;
}

// fused finalize + scatter, block-split; both sides use inline 49-elem bsum scan.
// blocks [0,NBX): row_fin/dinv/xd build.  blocks [NBX,NBX+NBS): cursor-atomic scatter.
__global__ __launch_bounds__(256) void k_finish(const int* __restrict__ edeg,
                                                const int* __restrict__ row_ptr,
                                                const int* __restrict__ bsum,
                                                int* __restrict__ row_fin,
                                                float* __restrict__ dinv,
                                                const float* __restrict__ x,
                                                f16* __restrict__ xd,
                                                const int* __restrict__ src,
                                                const int* __restrict__ dst,
                                                int* __restrict__ cur,
                                                ushort_t* __restrict__ csr) {
    __shared__ int pre[64];
    if (threadIdx.x < 64) {
        int l = threadIdx.x;
        int v = (l < NB_SCAN) ? bsum[l] : 0;
        int incl = v;
#pragma unroll
        for (int off = 1; off < 64; off <<= 1) {
            int tt = __shfl_up(incl, off, 64);
            if (l >= off) incl += tt;
        }
        pre[l] = incl - v;
    }
    __syncthreads();
    int b = blockIdx.x;
    if (b < NBX) {
        int wv = threadIdx.x >> 6, lane = threadIdx.x & 63;
        int i = b * 4 + wv;
        if (i >= N) return;
        int rp = row_ptr[i] + pre[i >> 10];
        float di = rsqrtf(1.0f + (float)edeg[i]);
        if (lane == 0) {
            row_fin[i] = rp;
            dinv[i] = di;
            if (i == 0) row_fin[N] = E;
        }
        xd[(size_t)i * 64 + lane] = (f16)(di * x[(size_t)i * 64 + lane]);
    } else {
        int e = (b - NBX) * 256 + threadIdx.x;
        if (e >= E) return;
        int d = dst[e];
        int slot = row_ptr[d] + pre[d >> 10] + atomicAdd(&cur[d], 1);
        csr[slot] = (ushort_t)src[e];
    }
}

// out[i] = f16( (BIAS? b : 0) + dinv[i] * ( tbl[i] + sum_e tbl[csr_e] ) )
// lane = (edge-slot sub 0..7, 16B-chunk fp 0..7); 32 edge slots/iter; 4 gathers in flight.
template <bool BIAS>
__global__ __launch_bounds__(256) void k_agg(const f16* __restrict__ tbl,
                                             const int* __restrict__ rp,
                                             const ushort_t* __restrict__ csr,
                                             const float* __restrict__ dinv,
                                             const float* __restrict__ bias,
                                             f16* __restrict__ outh) {
    int wv = threadIdx.x >> 6, l = threadIdx.x & 63;
    int sub = l >> 3, fp = l & 7;
    int node = blockIdx.x * 4 + wv;
    if (node >= N) return;
    int beg = rp[node], end = rp[node + 1];
    const f16x8* tv = (const f16x8*)tbl;
    f16x8 sv = tv[(size_t)node * 8 + fp];
    float a[8] = {0.f, 0.f, 0.f, 0.f, 0.f, 0.f, 0.f, 0.f};

    int e = beg;
    for (; e + 32 <= end; e += 32) {
        int s0 = csr[e + sub];
        int s1 = csr[e + 8 + sub];
        int s2 = csr[e + 16 + sub];
        int s3 = csr[e + 24 + sub];
        f16x8 v0 = tv[(size_t)s0 * 8 + fp];
        f16x8 v1 = tv[(size_t)s1 * 8 + fp];
        f16x8 v2 = tv[(size_t)s2 * 8 + fp];
        f16x8 v3 = tv[(size_t)s3 * 8 + fp];
#pragma unroll
        for (int j = 0; j < 8; ++j)
            a[j] += ((float)v0[j] + (float)v1[j]) + ((float)v2[j] + (float)v3[j]);
    }
    if (e < end) {
        int last = end - 1;
        int i0 = e + sub, i1 = e + 8 + sub, i2 = e + 16 + sub, i3 = e + 24 + sub;
        int s0 = csr[min(i0, last)];
        int s1 = csr[min(i1, last)];
        int s2 = csr[min(i2, last)];
        int s3 = csr[min(i3, last)];
        f16x8 v0 = tv[(size_t)s0 * 8 + fp];
        f16x8 v1 = tv[(size_t)s1 * 8 + fp];
        f16x8 v2 = tv[(size_t)s2 * 8 + fp];
        f16x8 v3 = tv[(size_t)s3 * 8 + fp];
        float m0 = i0 < end ? 1.f : 0.f;
        float m1 = i1 < end ? 1.f : 0.f;
        float m2 = i2 < end ? 1.f : 0.f;
        float m3 = i3 < end ? 1.f : 0.f;
#pragma unroll
        for (int j = 0; j < 8; ++j)
            a[j] += (m0 * (float)v0[j] + m1 * (float)v1[j]) +
                    (m2 * (float)v2[j] + m3 * (float)v3[j]);
    }
#pragma unroll
    for (int j = 0; j < 8; ++j) {
        a[j] += __shfl_xor(a[j], 8, 64);
        a[j] += __shfl_xor(a[j], 16, 64);
        a[j] += __shfl_xor(a[j], 32, 64);
    }
    float di = dinv[node];
    if (sub == 0) {
        f16x8 o;
#pragma unroll
        for (int j = 0; j < 8; ++j) {
            float r = di * ((float)sv[j] + a[j]);
            if (BIAS) r += bias[fp * 8 + j];
            o[j] = (f16)r;
        }
        *(f16x8*)(outh + (size_t)node * 64 + fp * 8) = o;
    }
}

// fused MFMA GEMM: h2d = f16( dinv ⊙ ( relu(xab @ W1 + b1) @ W2 ) )
// 64 nodes / block; wave w owns rows 16w..16w+15 end-to-end (no barrier).
__global__ __launch_bounds__(256) void k_gemm_mfma(const f16* __restrict__ xab,
                                                   const f16* __restrict__ W1f,
                                                   const float* __restrict__ b1,
                                                   const f16* __restrict__ W2f,
                                                   const float* __restrict__ dinv,
                                                   f16* __restrict__ h2d) {
    __shared__ f16 H1[64 * 128];   // 16 KB
    int t = threadIdx.x;
    int w = t >> 6, l = t & 63;
    int q = l >> 4, m = l & 15;
    int n0 = blockIdx.x * 64;
    int rbase = 16 * w;

    f16x8 afr0, afr1;
    {
        int row = n0 + rbase + m;
        if (row >= N) row = N - 1;
        const f16* rp_ = xab + (size_t)row * 64 + q * 8;
        afr0 = *(const f16x8*)(rp_);
        afr1 = *(const f16x8*)(rp_ + 32);
    }
    f32x4 acc[8];
#pragma unroll
    for (int c = 0; c < 8; ++c) acc[c] = (f32x4){0.f, 0.f, 0.f, 0.f};
    const f16x8* W1v = (const f16x8*)W1f;
#pragma unroll
    for (int c = 0; c < 8; ++c) {
        f16x8 b0 = W1v[(0 * 8 + c) * 64 + l];
        f16x8 b1v = W1v[(1 * 8 + c) * 64 + l];
        acc[c] = __builtin_amdgcn_mfma_f32_16x16x32_f16(afr0, b0, acc[c], 0, 0, 0);
        acc[c] = __builtin_amdgcn_mfma_f32_16x16x32_f16(afr1, b1v, acc[c], 0, 0, 0);
    }
#pragma unroll
    for (int c = 0; c < 8; ++c) {
        float bias = b1[16 * c + m];
#pragma unroll
        for (int r = 0; r < 4; ++r) {
            int row = rbase + 4 * q + r;
            int col = 16 * c + m;
            float hv = fmaxf(acc[c][r] + bias, 0.f);
            int addr = row * 256 + col * 2;
            addr ^= ((row & 3) << 4) ^ (((row >> 2) & 3) << 5);
            *(f16*)((char*)H1 + addr) = (f16)hv;
        }
    }
    f16x8 a2[4];
#pragma unroll
    for (int kk = 0; kk < 4; ++kk) {
        int row = rbase + m;
        int addr = row * 256 + kk * 64 + q * 16;
        addr ^= ((row & 3) << 4) ^ (((row >> 2) & 3) << 5);
        a2[kk] = *(const f16x8*)((char*)H1 + addr);
    }
    f32x4 acc2[4];
#pragma unroll
    for (int c = 0; c < 4; ++c) acc2[c] = (f32x4){0.f, 0.f, 0.f, 0.f};
    const f16x8* W2v = (const f16x8*)W2f;
#pragma unroll
    for (int c = 0; c < 4; ++c) {
#pragma unroll
        for (int kk = 0; kk < 4; ++kk) {
            f16x8 b = W2v[(kk * 4 + c) * 64 + l];
            acc2[c] = __builtin_amdgcn_mfma_f32_16x16x32_f16(a2[kk], b, acc2[c], 0, 0, 0);
        }
    }
#pragma unroll
    for (int r = 0; r < 4; ++r) {
        int n = n0 + rbase + 4 * q + r;
        if (n < N) {
            float di = dinv[n];
#pragma unroll
            for (int c = 0; c < 4; ++c)
                h2d[(size_t)n * 64 + 16 * c + m] = (f16)(di * acc2[c][r]);
        }
    }
}

// one block (4 waves) per graph; batch sorted -> binary search node range; o2 in f16
__global__ __launch_bounds__(256) void k_pool(const f16* __restrict__ o2h,
                                              const int* __restrict__ batch,
                                              float* __restrict__ out) {
    __shared__ float red[256];
    int g = blockIdx.x;
    int wv = threadIdx.x >> 6, lane = threadIdx.x & 63;
    int lo = 0, hi = N;
    while (lo < hi) { int m = (lo + hi) >> 1; if (batch[m] < g) lo = m + 1; else hi = m; }
    int start = lo;
    hi = N;
    while (lo < hi) { int m = (lo + hi) >> 1; if (batch[m] < g + 1) lo = m + 1; else hi = m; }
    int end = lo;
    float acc = 0.f;
    for (int n = start + wv; n < end; n += 4) acc += (float)o2h[(size_t)n * 64 + lane];
    red[threadIdx.x] = acc;
    __syncthreads();
    if (wv == 0) {
        float v = red[lane] + red[64 + lane] + red[128 + lane] + red[192 + lane];
        out[g * 64 + lane] = v / fmaxf((float)(end - start), 1.f);
    }
}

extern "C" void kernel_launch(void* const* d_in, const int* in_sizes, int n_in,
                              void* d_out, int out_size, void* d_ws, size_t ws_size,
                              hipStream_t stream) {
    const float* x     = (const float*)d_in[0];
    const int*   ei    = (const int*)d_in[1];
    const int*   batch = (const int*)d_in[2];
    const float* W1    = (const float*)d_in[3];
    const float* b1    = (const float*)d_in[4];
    const float* W2    = (const float*)d_in[5];
    const float* b2    = (const float*)d_in[6];
    float* out = (float*)d_out;

    const int* srcp = ei;        // edge_index[0]
    const int* dstp = ei + E;    // edge_index[1]

    char* ws = (char*)d_ws;
    int*      edeg    = (int*)     (ws + 0);          //   200,000 -> 200,704
    int*      cur     = (int*)     (ws + 200704);     //   200,000 -> 401,408 (zeroed with edeg)
    float*    dinv    = (float*)   (ws + 401408);     //   200,000 -> 602,112
    int*      row_ptr = (int*)     (ws + 602112);     //   200,004 -> 802,816
    int*      row_fin = (int*)     (ws + 802816);     //   200,004 -> 1,003,520
    int*      bsum    = (int*)     (ws + 1003520);    //       256 -> 1,004,032
    ushort_t* csr16   = (ushort_t*)(ws + 1004032);    // 1,600,000 -> 2,604,032
    f16*      xd      = (f16*)     (ws + 2604032);    // 6,400,000 -> 9,004,032
    f16*      xab     = (f16*)     (ws + 9004032);    // 6,400,000 -> 15,404,032
    f16*      h2d     = (f16*)     (ws + 15404032);   // 6,400,000 -> 21,804,032
    f16*      o2h     = xd;                           // xd dead after first agg
    f16*      W1f     = (f16*)     (ws + 21804032);   //    16,384 -> 21,820,416
    f16*      W2f     = (f16*)     (ws + 21820416);   //    16,384 -> 21,836,800

    dim3 B(256);

    k_zero<<<dim3(98), B, 0, stream>>>((int4*)edeg);
    k_deg<<<dim3(NBS), B, 0, stream>>>(dstp, edeg);
    k_scan1w<<<dim3(NB_SCAN + 64), B, 0, stream>>>(edeg, row_ptr, bsum, W1, W2, W1f, W2f);
    k_finish<<<dim3(NBX + NBS), B, 0, stream>>>(edeg, row_ptr, bsum, row_fin, dinv,
                                                x, xd, srcp, dstp, cur, csr16);

    k_agg<false><<<dim3(NBX), B, 0, stream>>>(xd, row_fin, csr16, dinv, nullptr, xab);
    k_gemm_mfma<<<dim3((N + 63) / 64), B, 0, stream>>>(xab, W1f, b1, W2f, dinv, h2d);
    k_agg<true><<<dim3(NBX), B, 0, stream>>>(h2d, row_fin, csr16, dinv, b2, o2h);
    k_pool<<<dim3(G), B, 0, stream>>>(o2h, batch, out);
}

// Round 12
// 142.472 us; speedup vs baseline: 1.1513x; 1.1513x over previous
//
#include <hip/hip_runtime.h>

typedef unsigned short ushort_t;
typedef unsigned int uint_t;
typedef _Float16 f16;
typedef _Float16 f16x8 __attribute__((ext_vector_type(8)));
typedef float f32x4 __attribute__((ext_vector_type(4)));

constexpr int N    = 50000;
constexpr int E    = 800000;
constexpr int G    = 512;
constexpr int SCAN_ITEMS = 1024;
constexpr int NB_SCAN = (N + SCAN_ITEMS - 1) / SCAN_ITEMS;   // 49
constexpr int NBX = (N + 3) / 4;          // 12500 node-parallel blocks

// zero edeg (50000 ints = 12500 int4)
__global__ void k_zero(int4* __restrict__ p) {
    int i = blockIdx.x * blockDim.x + threadIdx.x;
    if (i < 12500) p[i] = int4{0, 0, 0, 0};
}

// degree + per-edge rank capture (rank store is sequential, u16)
__global__ void k_deg(const int* __restrict__ dst, int* __restrict__ edeg,
                      ushort_t* __restrict__ rank) {
    int e = blockIdx.x * blockDim.x + threadIdx.x;
    if (e < E) rank[e] = (ushort_t)atomicAdd(&edeg[dst[e]], 1);
}

// block-level exclusive scan of edeg (1024 items / block); extra blocks repack W->f16 frags
__global__ __launch_bounds__(256) void k_scan1w(const int* __restrict__ edeg,
                                                int* __restrict__ row_ptr,
                                                int* __restrict__ bsum,
                                                const float* __restrict__ W1,
                                                const float* __restrict__ W2,
                                                f16* __restrict__ W1f,
                                                f16* __restrict__ W2f) {
    __shared__ int s[256];
    int t = threadIdx.x;
    if (blockIdx.x >= NB_SCAN) {
        int idx = (blockIdx.x - NB_SCAN) * 256 + t;
        if (idx < 8192) {
            int j = idx & 7, lane = (idx >> 3) & 63, c = (idx >> 9) & 7, kk = idx >> 12;
            int k = 32 * kk + 8 * (lane >> 4) + j, col = 16 * c + (lane & 15);
            W1f[idx] = (f16)W1[k * 128 + col];
        } else {
            int t2 = idx - 8192;
            int j = t2 & 7, lane = (t2 >> 3) & 63, c = (t2 >> 9) & 3, kk = (t2 >> 11) & 3;
            int k = 32 * kk + 8 * (lane >> 4) + j, col = 16 * c + (lane & 15);
            W2f[t2] = (f16)W2[k * 64 + col];
        }
        return;
    }
    int base = blockIdx.x * SCAN_ITEMS + t * 4;
    int v0 = (base + 0 < N) ? edeg[base + 0] : 0;
    int v1 = (base + 1 < N) ? edeg[base + 1] : 0;
    int v2 = (base + 2 < N) ? edeg[base + 2] : 0;
    int v3 = (base + 3 < N) ? edeg[base + 3] : 0;
    int tsum = v0 + v1 + v2 + v3;
    s[t] = tsum;
    __syncthreads();
    for (int off = 1; off < 256; off <<= 1) {
        int add = (t >= off) ? s[t - off] : 0;
        __syncthreads();
        s[t] += add;
        __syncthreads();
    }
    int texcl = s[t] - tsum;
    if (t == 255) bsum[blockIdx.x] = s[255];
    if (base + 0 < N) row_ptr[base + 0] = texcl;
    if (base + 1 < N) row_ptr[base + 1] = texcl + v0;
    if (base + 2 < N) row_ptr[base + 2] = texcl + v0 + v1;
    if (base + 3 < N) row_ptr[base + 3] = texcl + v0 + v1 + v2;
}

// finalize row_ptr (inline 49-elem bsum scan), dinv, xd = f16(dinv ⊙ x)
__global__ __launch_bounds__(256) void k_scan3x(const int* __restrict__ edeg,
                                                int* __restrict__ row_ptr,
                                                const int* __restrict__ bsum,
                                                float* __restrict__ dinv,
                                                const float* __restrict__ x,
                                                f16* __restrict__ xd) {
    __shared__ int pre[64];
    if (threadIdx.x < 64) {
        int l = threadIdx.x;
        int v = (l < NB_SCAN) ? bsum[l] : 0;
        int incl = v;
#pragma unroll
        for (int off = 1; off < 64; off <<= 1) {
            int tt = __shfl_up(incl, off, 64);
            if (l >= off) incl += tt;
        }
        pre[l] = incl - v;
    }
    __syncthreads();
    int wv = threadIdx.x >> 6, lane = threadIdx.x & 63;
    int i = blockIdx.x * 4 + wv;
    if (i >= N) return;
    int rp = row_ptr[i] + pre[i >> 10];            // SCAN_ITEMS = 1024
    float di = rsqrtf(1.0f + (float)edeg[i]);
    if (lane == 0) {
        row_ptr[i] = rp;
        dinv[i] = di;
        if (i == 0) row_ptr[N] = E;
    }
    xd[(size_t)i * 64 + lane] = (f16)(di * x[(size_t)i * 64 + lane]);
}

// non-atomic scatter: csr16[row_ptr[dst] + rank] = src  (u16 payload)
__global__ void k_scatter(const int* __restrict__ src, const int* __restrict__ dst,
                          const ushort_t* __restrict__ rank, const int* __restrict__ row_ptr,
                          ushort_t* __restrict__ csr) {
    int e = blockIdx.x * blockDim.x + threadIdx.x;
    if (e >= E) return;
    csr[row_ptr[dst[e]] + rank[e]] = (ushort_t)src[e];
}

// out[i] = f16( (BIAS? b : 0) + dinv[i] * ( tbl[i] + sum_e tbl[csr_e] ) )
// lane = (edge-slot sub 0..7, 16B-chunk fp 0..7).
// main: 32 slots/iter (4-deep); then one unmasked 16-slot block; then masked 16-slot.
template <bool BIAS>
__global__ __launch_bounds__(256) void k_agg(const f16* __restrict__ tbl,
                                             const int* __restrict__ rp,
                                             const ushort_t* __restrict__ csr,
                                             const float* __restrict__ dinv,
                                             const float* __restrict__ bias,
                                             f16* __restrict__ outh) {
    int wv = threadIdx.x >> 6, l = threadIdx.x & 63;
    int sub = l >> 3, fp = l & 7;
    int node = blockIdx.x * 4 + wv;
    if (node >= N) return;
    int beg = rp[node], end = rp[node + 1];
    const f16x8* tv = (const f16x8*)tbl;
    f16x8 sv = tv[(size_t)node * 8 + fp];
    float a[8] = {0.f, 0.f, 0.f, 0.f, 0.f, 0.f, 0.f, 0.f};

    int e = beg;
    for (; e + 32 <= end; e += 32) {                // heavy rows: 4 gathers in flight
        int s0 = csr[e + sub];
        int s1 = csr[e + 8 + sub];
        int s2 = csr[e + 16 + sub];
        int s3 = csr[e + 24 + sub];
        f16x8 v0 = tv[(size_t)s0 * 8 + fp];
        f16x8 v1 = tv[(size_t)s1 * 8 + fp];
        f16x8 v2 = tv[(size_t)s2 * 8 + fp];
        f16x8 v3 = tv[(size_t)s3 * 8 + fp];
#pragma unroll
        for (int j = 0; j < 8; ++j)
            a[j] += ((float)v0[j] + (float)v1[j]) + ((float)v2[j] + (float)v3[j]);
    }
    if (e + 16 <= end) {                            // median rows: unmasked 16-slot
        int s0 = csr[e + sub];
        int s1 = csr[e + 8 + sub];
        f16x8 v0 = tv[(size_t)s0 * 8 + fp];
        f16x8 v1 = tv[(size_t)s1 * 8 + fp];
#pragma unroll
        for (int j = 0; j < 8; ++j)
            a[j] += (float)v0[j] + (float)v1[j];
        e += 16;
    }
    if (e < end) {                                  // masked 16-slot tail
        int last = end - 1;
        int i0 = e + sub, i1 = e + 8 + sub;
        int s0 = csr[min(i0, last)];
        int s1 = csr[min(i1, last)];
        f16x8 v0 = tv[(size_t)s0 * 8 + fp];
        f16x8 v1 = tv[(size_t)s1 * 8 + fp];
        float m0 = i0 < end ? 1.f : 0.f;
        float m1 = i1 < end ? 1.f : 0.f;
#pragma unroll
        for (int j = 0; j < 8; ++j)
            a[j] += m0 * (float)v0[j] + m1 * (float)v1[j];
    }
#pragma unroll
    for (int j = 0; j < 8; ++j) {
        a[j] += __shfl_xor(a[j], 8, 64);
        a[j] += __shfl_xor(a[j], 16, 64);
        a[j] += __shfl_xor(a[j], 32, 64);
    }
    float di = dinv[node];
    if (sub == 0) {
        f16x8 o;
#pragma unroll
        for (int j = 0; j < 8; ++j) {
            float r = di * ((float)sv[j] + a[j]);
            if (BIAS) r += bias[fp * 8 + j];
            o[j] = (f16)r;
        }
        *(f16x8*)(outh + (size_t)node * 64 + fp * 8) = o;
    }
}

// fused MFMA GEMM: h2d = f16( dinv ⊙ ( relu(xab @ W1 + b1) @ W2 ) )
// 64 nodes / block; wave w owns rows 16w..16w+15 end-to-end (no barrier).
__global__ __launch_bounds__(256) void k_gemm_mfma(const f16* __restrict__ xab,
                                                   const f16* __restrict__ W1f,
                                                   const float* __restrict__ b1,
                                                   const f16* __restrict__ W2f,
                                                   const float* __restrict__ dinv,
                                                   f16* __restrict__ h2d) {
    __shared__ f16 H1[64 * 128];   // 16 KB
    int t = threadIdx.x;
    int w = t >> 6, l = t & 63;
    int q = l >> 4, m = l & 15;
    int n0 = blockIdx.x * 64;
    int rbase = 16 * w;

    f16x8 afr0, afr1;
    {
        int row = n0 + rbase + m;
        if (row >= N) row = N - 1;
        const f16* rp_ = xab + (size_t)row * 64 + q * 8;
        afr0 = *(const f16x8*)(rp_);
        afr1 = *(const f16x8*)(rp_ + 32);
    }
    f32x4 acc[8];
#pragma unroll
    for (int c = 0; c < 8; ++c) acc[c] = (f32x4){0.f, 0.f, 0.f, 0.f};
    const f16x8* W1v = (const f16x8*)W1f;
#pragma unroll
    for (int c = 0; c < 8; ++c) {
        f16x8 b0 = W1v[(0 * 8 + c) * 64 + l];
        f16x8 b1v = W1v[(1 * 8 + c) * 64 + l];
        acc[c] = __builtin_amdgcn_mfma_f32_16x16x32_f16(afr0, b0, acc[c], 0, 0, 0);
        acc[c] = __builtin_amdgcn_mfma_f32_16x16x32_f16(afr1, b1v, acc[c], 0, 0, 0);
    }
#pragma unroll
    for (int c = 0; c < 8; ++c) {
        float bias = b1[16 * c + m];
#pragma unroll
        for (int r = 0; r < 4; ++r) {
            int row = rbase + 4 * q + r;
            int col = 16 * c + m;
            float hv = fmaxf(acc[c][r] + bias, 0.f);
            int addr = row * 256 + col * 2;
            addr ^= ((row & 3) << 4) ^ (((row >> 2) & 3) << 5);
            *(f16*)((char*)H1 + addr) = (f16)hv;
        }
    }
    f16x8 a2[4];
#pragma unroll
    for (int kk = 0; kk < 4; ++kk) {
        int row = rbase + m;
        int addr = row * 256 + kk * 64 + q * 16;
        addr ^= ((row & 3) << 4) ^ (((row >> 2) & 3) << 5);
        a2[kk] = *(const f16x8*)((char*)H1 + addr);
    }
    f32x4 acc2[4];
#pragma unroll
    for (int c = 0; c < 4; ++c) acc2[c] = (f32x4){0.f, 0.f, 0.f, 0.f};
    const f16x8* W2v = (const f16x8*)W2f;
#pragma unroll
    for (int c = 0; c < 4; ++c) {
#pragma unroll
        for (int kk = 0; kk < 4; ++kk) {
            f16x8 b = W2v[(kk * 4 + c) * 64 + l];
            acc2[c] = __builtin_amdgcn_mfma_f32_16x16x32_f16(a2[kk], b, acc2[c], 0, 0, 0);
        }
    }
#pragma unroll
    for (int r = 0; r < 4; ++r) {
        int n = n0 + rbase + 4 * q + r;
        if (n < N) {
            float di = dinv[n];
#pragma unroll
            for (int c = 0; c < 4; ++c)
                h2d[(size_t)n * 64 + 16 * c + m] = (f16)(di * acc2[c][r]);
        }
    }
}

// one block (4 waves) per graph; batch sorted -> binary search node range; o2 in f16
__global__ __launch_bounds__(256) void k_pool(const f16* __restrict__ o2h,
                                              const int* __restrict__ batch,
                                              float* __restrict__ out) {
    __shared__ float red[256];
    int g = blockIdx.x;
    int wv = threadIdx.x >> 6, lane = threadIdx.x & 63;
    int lo = 0, hi = N;
    while (lo < hi) { int m = (lo + hi) >> 1; if (batch[m] < g) lo = m + 1; else hi = m; }
    int start = lo;
    hi = N;
    while (lo < hi) { int m = (lo + hi) >> 1; if (batch[m] < g + 1) lo = m + 1; else hi = m; }
    int end = lo;
    float acc = 0.f;
    for (int n = start + wv; n < end; n += 4) acc += (float)o2h[(size_t)n * 64 + lane];
    red[threadIdx.x] = acc;
    __syncthreads();
    if (wv == 0) {
        float v = red[lane] + red[64 + lane] + red[128 + lane] + red[192 + lane];
        out[g * 64 + lane] = v / fmaxf((float)(end - start), 1.f);
    }
}

extern "C" void kernel_launch(void* const* d_in, const int* in_sizes, int n_in,
                              void* d_out, int out_size, void* d_ws, size_t ws_size,
                              hipStream_t stream) {
    const float* x     = (const float*)d_in[0];
    const int*   ei    = (const int*)d_in[1];
    const int*   batch = (const int*)d_in[2];
    const float* W1    = (const float*)d_in[3];
    const float* b1    = (const float*)d_in[4];
    const float* W2    = (const float*)d_in[5];
    const float* b2    = (const float*)d_in[6];
    float* out = (float*)d_out;

    const int* srcp = ei;        // edge_index[0]
    const int* dstp = ei + E;    // edge_index[1]

    char* ws = (char*)d_ws;
    int*      edeg    = (int*)     (ws + 0);          //   200,000 -> 200,704
    ushort_t* rank16  = (ushort_t*)(ws + 200704);     // 1,600,000 -> 1,801,216
    float*    dinv    = (float*)   (ws + 1801216);    //   200,000 -> 2,001,920
    int*      row_ptr = (int*)     (ws + 2001920);    //   200,004 -> 2,202,624
    int*      bsum    = (int*)     (ws + 2202624);    //       256 -> 2,203,136
    ushort_t* csr16   = (ushort_t*)(ws + 2203136);    // 1,600,000 -> 3,803,648
    f16*      xd      = (f16*)     (ws + 3803648);    // 6,400,000 -> 10,203,648
    f16*      xab     = (f16*)     (ws + 10203648);   // 6,400,000 -> 16,603,648
    f16*      h2d     = (f16*)     (ws + 16603648);   // 6,400,000 -> 23,003,648
    f16*      o2h     = xd;                           // xd dead after first agg
    f16*      W1f     = (f16*)     (ws + 23003648);   //    16,384 -> 23,020,032
    f16*      W2f     = (f16*)     (ws + 23020032);   //    16,384 -> 23,036,416

    dim3 B(256);

    k_zero<<<dim3(49), B, 0, stream>>>((int4*)edeg);
    k_deg<<<dim3((E + 255) / 256), B, 0, stream>>>(dstp, edeg, rank16);
    k_scan1w<<<dim3(NB_SCAN + 64), B, 0, stream>>>(edeg, row_ptr, bsum, W1, W2, W1f, W2f);
    k_scan3x<<<dim3(NBX), B, 0, stream>>>(edeg, row_ptr, bsum, dinv, x, xd);
    k_scatter<<<dim3((E + 255) / 256), B, 0, stream>>>(srcp, dstp, rank16, row_ptr, csr16);

    k_agg<false><<<dim3(NBX), B, 0, stream>>>(xd, row_ptr, csr16, dinv, nullptr, xab);
    k_gemm_mfma<<<dim3((N + 63) / 64), B, 0, stream>>>(xab, W1f, b1, W2f, dinv, h2d);
    k_agg<true><<<dim3(NBX), B, 0, stream>>>(h2d, row_ptr, csr16, dinv, b2, o2h);
    k_pool<<<dim3(G), B, 0, stream>>>(o2h, batch, out);
}